// Round 4
// baseline (731.918 us; speedup 1.0000x reference)
//
#include <hip/hip_runtime.h>

namespace {

constexpr int kB  = 16;
constexpr int kNC = 31;
constexpr int kNX = 256;   // rows (H)
constexpr int kNY = 256;   // cols (W)
constexpr int kNO = 3;
constexpr int kKS = 17;
constexpr int NOC = kNO * kNC;   // 93

constexpr int TX = 64;           // output cols per block
constexpr int TY = 32;           // output rows per block
constexpr int HTY = TY + 8;      // 40 staged rows (halo +-4)
constexpr int XP  = 84;          // tile pitch: mult of 4 -> b128-aligned rows
constexpr int WROW = 12;         // padded weight row -> 16B-aligned rows

// ---------------------------------------------------------------------------
// prep: ReLU sparse kernel values into d_ws (rows padded to 12) and decode the
// per-(order,channel) horizontal shift so = cx-4 in [0,8] from locations.
// ---------------------------------------------------------------------------
__global__ void prep(const float* __restrict__ vk, const int* __restrict__ loc,
                     float* __restrict__ wrel, int* __restrict__ soTab)
{
    int i = blockIdx.x * 256 + threadIdx.x;
    if (i < NOC * 9 * WROW) {
        int row = i / WROW;            // row = oc*9 + dy
        int dx  = i - row * WROW;
        float v = 0.0f;
        if (dx < 9) {
            float t = vk[row * 9 + dx];
            v = t > 0.0f ? t : 0.0f;
        }
        wrel[i] = v;
    }
    if (i < NOC) {
        // locations[oc*81] = ((oc*17 + 4)*17) + cx - 4  ->  recover cx
        int cx = loc[i * 81] - (i * kKS + 4) * kKS + 4;
        soTab[i] = cx - 4;             // so in [0,8]
    }
}

// One (batch, order, 64x32 tile) per block. 256 threads: 8 across x (8 cols
// each), 32 down y. Per thread: 8 accumulators. R1-proven codegen pattern:
// scalar LDS reads into statically-indexed xr[16], inline FMAs, no switch,
// no helper-function pointer passing (those caused SROA failure / scratch).
__global__ __launch_bounds__(256, 6)
void disperse_conv(const float* __restrict__ x,
                   const float* __restrict__ wrel,
                   const int* __restrict__ soTab,
                   float* __restrict__ out)
{
    __shared__ __align__(16) float xtile[HTY * XP];   // 13,440 B

    const int tid = threadIdx.x;
    const int x0 = blockIdx.x * TX;
    const int y0 = blockIdx.y * TY;
    const int bz = blockIdx.z;         // 48 = kB * kNO
    const int b  = bz & 15;            // bz % 16
    const int o  = bz >> 4;            // bz / 16

    const int tx = tid & 7;            // 8 threads across x
    const int ty = tid >> 3;           // 32 threads down y
    const int xo = tx * 8;             // 8 consecutive output cols per thread

    float acc[8];
    #pragma unroll
    for (int j = 0; j < 8; ++j) acc[j] = 0.0f;

    for (int c = 0; c < kNC; ++c) {
        __syncthreads();   // protect previous tile before overwrite
        // --- stage x tile: rows y0-4..y0+35, cols x0-8..x0+71, zero-padded ---
        const float* xc = x + (size_t)(b * kNC + c) * kNX * kNY;
        #pragma unroll
        for (int it = 0; it < 4; ++it) {           // 800 float4 over 256 threads
            int i = it * 256 + tid;
            if (i < HTY * 20) {
                int r = i / 20;
                int k = i - r * 20;
                int gy = y0 - 4 + r;
                int gx = x0 - 8 + k * 4;           // mult of 4: aligned global f4
                float4 v = make_float4(0.f, 0.f, 0.f, 0.f);
                if ((unsigned)gy < (unsigned)kNX && (unsigned)gx < (unsigned)kNY)
                    v = *(const float4*)(xc + (size_t)gy * kNY + gx);
                *(float4*)&xtile[r * XP + k * 4] = v;   // LDS b128, aligned
            }
        }
        __syncthreads();

        const int so = soTab[o * kNC + c];         // block-uniform, in [0,8]
        const float* wch = wrel + (size_t)((o * kNC + c) * 9) * WROW;

        #pragma unroll 1
        for (int dy = 0; dy < 9; ++dy) {
            // scalar LDS reads from the so-folded pointer; xr indexing static
            const float* xt = &xtile[(ty + dy) * XP + xo + so];
            float xr[16];
            #pragma unroll
            for (int i = 0; i < 16; ++i) xr[i] = xt[i];

            // weights: block-uniform 16B-aligned loads, used as named components
            const float4 wa = *(const float4*)(wch + dy * WROW);      // d=0..3
            const float4 wb = *(const float4*)(wch + dy * WROW + 4);  // d=4..7
            const float  w8 = wch[dy * WROW + 8];                     // d=8

            #pragma unroll
            for (int j = 0; j < 8; ++j) acc[j] = fmaf(wa.x, xr[j + 0], acc[j]);
            #pragma unroll
            for (int j = 0; j < 8; ++j) acc[j] = fmaf(wa.y, xr[j + 1], acc[j]);
            #pragma unroll
            for (int j = 0; j < 8; ++j) acc[j] = fmaf(wa.z, xr[j + 2], acc[j]);
            #pragma unroll
            for (int j = 0; j < 8; ++j) acc[j] = fmaf(wa.w, xr[j + 3], acc[j]);
            #pragma unroll
            for (int j = 0; j < 8; ++j) acc[j] = fmaf(wb.x, xr[j + 4], acc[j]);
            #pragma unroll
            for (int j = 0; j < 8; ++j) acc[j] = fmaf(wb.y, xr[j + 5], acc[j]);
            #pragma unroll
            for (int j = 0; j < 8; ++j) acc[j] = fmaf(wb.z, xr[j + 6], acc[j]);
            #pragma unroll
            for (int j = 0; j < 8; ++j) acc[j] = fmaf(wb.w, xr[j + 7], acc[j]);
            #pragma unroll
            for (int j = 0; j < 8; ++j) acc[j] = fmaf(w8,   xr[j + 8], acc[j]);
        }
    }

    // --- epilogue: 8 cols per thread, two float4 stores ---
    size_t base = (((size_t)b * kNO + o) * kNX + (size_t)(y0 + ty)) * kNY
                  + (size_t)(x0 + xo);
    *(float4*)(out + base)     = make_float4(acc[0], acc[1], acc[2], acc[3]);
    *(float4*)(out + base + 4) = make_float4(acc[4], acc[5], acc[6], acc[7]);
}

} // namespace

extern "C" void kernel_launch(void* const* d_in, const int* in_sizes, int n_in,
                              void* d_out, int out_size, void* d_ws, size_t ws_size,
                              hipStream_t stream)
{
    const float* x  = (const float*)d_in[0];
    const float* vk = (const float*)d_in[1];
    const int* loc  = (const int*)d_in[2];
    float* outp = (float*)d_out;

    float* wrel = (float*)d_ws;                       // 93*9*12 floats = 40,176 B
    int*   soTab = (int*)(wrel + NOC * 9 * WROW);     // 93 ints

    dim3 pgrid((NOC * 9 * WROW + 255) / 256);
    hipLaunchKernelGGL(prep, pgrid, dim3(256), 0, stream, vk, loc, wrel, soTab);

    dim3 grid(kNY / TX, kNX / TY, kB * kNO);   // (4, 8, 48) = 1536 blocks
    hipLaunchKernelGGL(disperse_conv, grid, dim3(256), 0, stream,
                       x, wrel, soTab, outp);
}

// Round 5
// 479.561 us; speedup vs baseline: 1.5262x; 1.5262x over previous
//
#include <hip/hip_runtime.h>

namespace {

constexpr int kB  = 16;
constexpr int kNC = 31;
constexpr int kNX = 256;   // rows (H)
constexpr int kNY = 256;   // cols (W)
constexpr int kNO = 3;
constexpr int kKS = 17;
constexpr int NOC = kNO * kNC;   // 93

constexpr int TX = 64;           // output cols per block
constexpr int TY = 32;           // output rows per block
constexpr int HTY = TY + 8;      // 40 staged rows (halo +-4)
// ODD pitch: 85*ty mod 8 = 5ty hits all 8 residues -> lane banks spread over
// all 32 banks, only 2-way aliasing (free). XP=84 put ALL lanes on addr%4==const
// -> 8 banks -> 8-way conflict (the R4 2.5e8 conflict counter).
constexpr int XP  = 85;
constexpr int WROW = 12;         // padded weight row -> 16B-aligned rows

// ---------------------------------------------------------------------------
// prep: ReLU sparse kernel values into d_ws (rows padded to 12) and decode the
// per-(order,channel) horizontal shift so = cx-4 in [0,8] from locations.
// ---------------------------------------------------------------------------
__global__ void prep(const float* __restrict__ vk, const int* __restrict__ loc,
                     float* __restrict__ wrel, int* __restrict__ soTab)
{
    int i = blockIdx.x * 256 + threadIdx.x;
    if (i < NOC * 9 * WROW) {
        int row = i / WROW;            // row = oc*9 + dy
        int dx  = i - row * WROW;
        float v = 0.0f;
        if (dx < 9) {
            float t = vk[row * 9 + dx];
            v = t > 0.0f ? t : 0.0f;
        }
        wrel[i] = v;
    }
    if (i < NOC) {
        // locations[oc*81] = ((oc*17 + 4)*17) + cx - 4  ->  recover cx
        int cx = loc[i * 81] - (i * kKS + 4) * kKS + 4;
        soTab[i] = cx - 4;             // so in [0,8]
    }
}

// One (batch, order, 64x32 tile) per block. 256 threads: 8 across x (8 cols
// each), 32 down y. Scratch-free codegen pattern from R4 (scalar LDS reads
// into statically-indexed xr[16], inline FMAs, no switch).
__global__ __launch_bounds__(256, 6)
void disperse_conv(const float* __restrict__ x,
                   const float* __restrict__ wrel,
                   const int* __restrict__ soTab,
                   float* __restrict__ out)
{
    __shared__ float xtile[HTY * XP];   // 13,600 B

    const int tid = threadIdx.x;
    const int x0 = blockIdx.x * TX;
    const int y0 = blockIdx.y * TY;
    const int bz = blockIdx.z;         // 48 = kB * kNO, order-adjacent: bz = b*3+o
    const int b  = bz / 3;             // scalar magic-mul
    const int o  = bz - 3 * b;         // 3 orders of same (b,tile) dispatch-adjacent
                                       // -> L2/L3 absorbs the 3x x re-read

    const int tx = tid & 7;            // 8 threads across x
    const int ty = tid >> 3;           // 32 threads down y
    const int xo = tx * 8;             // 8 consecutive output cols per thread

    float acc[8];
    #pragma unroll
    for (int j = 0; j < 8; ++j) acc[j] = 0.0f;

    for (int c = 0; c < kNC; ++c) {
        __syncthreads();   // protect previous tile before overwrite
        // --- stage x tile: rows y0-4..y0+35, cols x0-8..x0+71, zero-padded ---
        const float* xc = x + (size_t)(b * kNC + c) * kNX * kNY;
        #pragma unroll
        for (int it = 0; it < 4; ++it) {           // 800 float4 over 256 threads
            int i = it * 256 + tid;
            if (i < HTY * 20) {
                int r = i / 20;
                int k = i - r * 20;
                int gy = y0 - 4 + r;
                int gx = x0 - 8 + k * 4;           // mult of 4: aligned global f4
                float4 v = make_float4(0.f, 0.f, 0.f, 0.f);
                if ((unsigned)gy < (unsigned)kNX && (unsigned)gx < (unsigned)kNY)
                    v = *(const float4*)(xc + (size_t)gy * kNY + gx);
                // odd pitch -> no 16B alignment; 4 scalar LDS writes (cheap:
                // 12.5/thread/channel vs 144 reads)
                float* d = &xtile[r * XP + k * 4];
                d[0] = v.x; d[1] = v.y; d[2] = v.z; d[3] = v.w;
            }
        }
        __syncthreads();

        const int so = soTab[o * kNC + c];         // block-uniform, in [0,8]
        const float* wch = wrel + (size_t)((o * kNC + c) * 9) * WROW;

        #pragma unroll 1
        for (int dy = 0; dy < 9; ++dy) {
            // scalar LDS reads from the so-folded pointer; xr indexing static
            const float* xt = &xtile[(ty + dy) * XP + xo + so];
            float xr[16];
            #pragma unroll
            for (int i = 0; i < 16; ++i) xr[i] = xt[i];

            // weights: block-uniform 16B-aligned loads -> scalar constant cache
            const float4 wa = *(const float4*)(wch + dy * WROW);      // d=0..3
            const float4 wb = *(const float4*)(wch + dy * WROW + 4);  // d=4..7
            const float  w8 = wch[dy * WROW + 8];                     // d=8

            #pragma unroll
            for (int j = 0; j < 8; ++j) acc[j] = fmaf(wa.x, xr[j + 0], acc[j]);
            #pragma unroll
            for (int j = 0; j < 8; ++j) acc[j] = fmaf(wa.y, xr[j + 1], acc[j]);
            #pragma unroll
            for (int j = 0; j < 8; ++j) acc[j] = fmaf(wa.z, xr[j + 2], acc[j]);
            #pragma unroll
            for (int j = 0; j < 8; ++j) acc[j] = fmaf(wa.w, xr[j + 3], acc[j]);
            #pragma unroll
            for (int j = 0; j < 8; ++j) acc[j] = fmaf(wb.x, xr[j + 4], acc[j]);
            #pragma unroll
            for (int j = 0; j < 8; ++j) acc[j] = fmaf(wb.y, xr[j + 5], acc[j]);
            #pragma unroll
            for (int j = 0; j < 8; ++j) acc[j] = fmaf(wb.z, xr[j + 6], acc[j]);
            #pragma unroll
            for (int j = 0; j < 8; ++j) acc[j] = fmaf(wb.w, xr[j + 7], acc[j]);
            #pragma unroll
            for (int j = 0; j < 8; ++j) acc[j] = fmaf(w8,   xr[j + 8], acc[j]);
        }
    }

    // --- epilogue: 8 cols per thread, two float4 stores ---
    size_t base = (((size_t)b * kNO + o) * kNX + (size_t)(y0 + ty)) * kNY
                  + (size_t)(x0 + xo);
    *(float4*)(out + base)     = make_float4(acc[0], acc[1], acc[2], acc[3]);
    *(float4*)(out + base + 4) = make_float4(acc[4], acc[5], acc[6], acc[7]);
}

} // namespace

extern "C" void kernel_launch(void* const* d_in, const int* in_sizes, int n_in,
                              void* d_out, int out_size, void* d_ws, size_t ws_size,
                              hipStream_t stream)
{
    const float* x  = (const float*)d_in[0];
    const float* vk = (const float*)d_in[1];
    const int* loc  = (const int*)d_in[2];
    float* outp = (float*)d_out;

    float* wrel = (float*)d_ws;                       // 93*9*12 floats = 40,176 B
    int*   soTab = (int*)(wrel + NOC * 9 * WROW);     // 93 ints

    dim3 pgrid((NOC * 9 * WROW + 255) / 256);
    hipLaunchKernelGGL(prep, pgrid, dim3(256), 0, stream, vk, loc, wrel, soTab);

    dim3 grid(kNY / TX, kNX / TY, kB * kNO);   // (4, 8, 48) = 1536 blocks
    hipLaunchKernelGGL(disperse_conv, grid, dim3(256), 0, stream,
                       x, wrel, soTab, outp);
}

// Round 6
// 447.863 us; speedup vs baseline: 1.6342x; 1.0708x over previous
//
#include <hip/hip_runtime.h>

namespace {

constexpr int kB  = 16;
constexpr int kNC = 31;
constexpr int kNX = 256;   // rows (H)
constexpr int kNY = 256;   // cols (W)
constexpr int kNO = 3;
constexpr int kKS = 17;
constexpr int NOC = kNO * kNC;   // 93

constexpr int TX = 64;           // output cols per block
constexpr int TY = 64;           // output rows per block
constexpr int HTY = TY + 8;      // 72 staged rows (halo +-4)
constexpr int TCOL = 76;         // staged cols (19 float4), covers k' in [0,76)
constexpr int XP   = 80;         // pitch (floats): mult of 4 -> all b128 aligned;
                                 // read quad=(4ty+5m+tx)%8, tx spans mod 8 -> even
constexpr int W12  = 12;         // expanded taps (9 + residual shift 0..3)

// ---------------------------------------------------------------------------
// prep: expand each 9-tap weight row to 12 taps with the residual shift rs
// pre-applied (w12[d'] = relu(w[d'-rs]) for d' in [rs,rs+9), else 0), and
// write soaTab[oc] = so & ~3 (the aligned part of the shift, used in staging).
// ---------------------------------------------------------------------------
__global__ void prep(const float* __restrict__ vk, const int* __restrict__ loc,
                     float* __restrict__ w12, int* __restrict__ soaTab)
{
    int i = blockIdx.x * 256 + threadIdx.x;
    if (i < NOC * 9 * W12) {
        int row = i / W12;             // row = oc*9 + dy
        int dp  = i - row * W12;       // d' in [0,12)
        int oc  = row / 9;
        // locations[oc*81] = ((oc*17 + 4)*17) + cx - 4  ->  so = cx - 4
        int so = loc[oc * 81] - (oc * kKS + 4) * kKS;   // in [0,8]
        int rs = so & 3;
        float v = 0.0f;
        if (dp >= rs && dp < rs + 9) {
            float t = vk[row * 9 + (dp - rs)];
            v = t > 0.0f ? t : 0.0f;
        }
        w12[i] = v;
    }
    if (i < NOC) {
        int so = loc[i * 81] - (i * kKS + 4) * kKS;
        soaTab[i] = so & ~3;           // in {0,4,8}
    }
}

// One (batch, order, 64x64 tile) per block. 256 threads as 16x16: each thread
// owns 4 cols x 4 rows. Tile staged pre-shifted by soa -> compute reads are
// STATIC aligned ds_read_b128; residual shift lives in the 12-tap weights.
__global__ __launch_bounds__(256, 3)
void disperse_conv(const float* __restrict__ x,
                   const float* __restrict__ w12,
                   const int* __restrict__ soaTab,
                   float* __restrict__ out)
{
    __shared__ __align__(16) float xtile[HTY * XP];   // 23,040 B

    const int tid = threadIdx.x;
    const int x0 = blockIdx.x * TX;
    const int y0 = blockIdx.y * TY;
    const int bz = blockIdx.z;         // 48, order-adjacent: bz = b*3 + o
    const int b  = bz / 3;             // -> 3 orders of same (b,tile) run
    const int o  = bz - 3 * b;         //    together, L2/L3 absorbs x re-read

    const int tx = tid & 15;           // 16 threads across x
    const int ty = tid >> 4;           // 16 threads down y
    const int xo = tx * 4;             // 4 consecutive output cols per thread

    float acc[4][4];
    #pragma unroll
    for (int jr = 0; jr < 4; ++jr)
        #pragma unroll
        for (int jj = 0; jj < 4; ++jj)
            acc[jr][jj] = 0.0f;

    for (int c = 0; c < kNC; ++c) {
        const int soa = soaTab[o * kNC + c];           // block-uniform {0,4,8}
        const float* wch = w12 + (size_t)((o * kNC + c) * 9) * W12;
        const float* xc  = x + (size_t)(b * kNC + c) * kNX * kNY;

        __syncthreads();   // protect previous tile before overwrite
        // --- stage pre-shifted tile: LDS[r][k'] = x[y0-4+r][x0+soa-8+k'],
        //     72 rows x 19 float4; everything 16B-aligned ---
        #pragma unroll
        for (int it = 0; it < 6; ++it) {               // 1368 f4 over 256 thr
            int i = it * 256 + tid;
            if (i < HTY * 19) {
                int r  = i / 19;
                int mc = i - r * 19;
                int gy = y0 - 4 + r;
                int gx = x0 + soa - 8 + mc * 4;        // mult of 4; f4 never
                float4 v = make_float4(0.f, 0.f, 0.f, 0.f);   // straddles edge
                if ((unsigned)gy < (unsigned)kNX && (unsigned)gx < (unsigned)kNY)
                    v = *(const float4*)(xc + (size_t)gy * kNY + gx);
                *(float4*)&xtile[r * XP + mc * 4] = v; // aligned b128 write
            }
        }
        __syncthreads();

        // --- compute: input rows m=0..11 feed output rows jr=0..3 (dy=m-jr) ---
        #pragma unroll
        for (int m = 0; m < 12; ++m) {
            const int row = ty * 4 + m;
            const float* p = &xtile[row * XP + xo];    // provably 16B aligned
            const float4 q0 = *(const float4*)(p);
            const float4 q1 = *(const float4*)(p + 4);
            const float4 q2 = *(const float4*)(p + 8);
            const float4 q3 = *(const float4*)(p + 12);
            const float xr[16] = { q0.x, q0.y, q0.z, q0.w,
                                   q1.x, q1.y, q1.z, q1.w,
                                   q2.x, q2.y, q2.z, q2.w,
                                   q3.x, q3.y, q3.z, q3.w };

            #pragma unroll
            for (int jr = 0; jr < 4; ++jr) {
                const int dy = m - jr;
                if (dy < 0 || dy >= 9) continue;       // folds at compile time
                // 12 expanded taps, block-uniform -> scalar constant cache
                const float* wr = wch + dy * W12;
                const float4 wa = *(const float4*)(wr);
                const float4 wb = *(const float4*)(wr + 4);
                const float4 wc = *(const float4*)(wr + 8);

                #pragma unroll
                for (int jj = 0; jj < 4; ++jj) {
                    float a = acc[jr][jj];
                    a = fmaf(wa.x, xr[jj + 0], a);
                    a = fmaf(wa.y, xr[jj + 1], a);
                    a = fmaf(wa.z, xr[jj + 2], a);
                    a = fmaf(wa.w, xr[jj + 3], a);
                    a = fmaf(wb.x, xr[jj + 4], a);
                    a = fmaf(wb.y, xr[jj + 5], a);
                    a = fmaf(wb.z, xr[jj + 6], a);
                    a = fmaf(wb.w, xr[jj + 7], a);
                    a = fmaf(wc.x, xr[jj + 8], a);
                    a = fmaf(wc.y, xr[jj + 9], a);
                    a = fmaf(wc.z, xr[jj + 10], a);
                    a = fmaf(wc.w, xr[jj + 11], a);
                    acc[jr][jj] = a;
                }
            }
        }
    }

    // --- epilogue: 4 rows x 4 cols per thread, aligned float4 stores ---
    #pragma unroll
    for (int jr = 0; jr < 4; ++jr) {
        size_t base = (((size_t)b * kNO + o) * kNX + (size_t)(y0 + ty * 4 + jr)) * kNY
                      + (size_t)(x0 + xo);
        *(float4*)(out + base) = make_float4(acc[jr][0], acc[jr][1],
                                             acc[jr][2], acc[jr][3]);
    }
}

} // namespace

extern "C" void kernel_launch(void* const* d_in, const int* in_sizes, int n_in,
                              void* d_out, int out_size, void* d_ws, size_t ws_size,
                              hipStream_t stream)
{
    const float* x  = (const float*)d_in[0];
    const float* vk = (const float*)d_in[1];
    const int* loc  = (const int*)d_in[2];
    float* outp = (float*)d_out;

    float* w12 = (float*)d_ws;                        // 93*9*12 floats = 40,176 B
    int*   soaTab = (int*)(w12 + NOC * 9 * W12);      // 93 ints

    dim3 pgrid((NOC * 9 * W12 + 255) / 256);
    hipLaunchKernelGGL(prep, pgrid, dim3(256), 0, stream, vk, loc, w12, soaTab);

    dim3 grid(kNY / TX, kNX / TY, kB * kNO);   // (4, 4, 48) = 768 blocks
    hipLaunchKernelGGL(disperse_conv, grid, dim3(256), 0, stream,
                       x, w12, soaTab, outp);
}